// Round 1
// 577.612 us; speedup vs baseline: 1.0157x; 1.0157x over previous
//
#include <hip/hip_runtime.h>

#define LD_   16384
#define LU_   65536
#define N_    8
#define DIN   256
#define DOUT  128
#define K_    3
#define M_    (LD_ * N_)   // 131072 rows through the MLP

typedef short bf16x8 __attribute__((ext_vector_type(8)));
typedef float f32x4  __attribute__((ext_vector_type(4)));

// fp32 -> bf16 round-to-nearest-even (inputs finite, no NaN handling)
__device__ __forceinline__ unsigned short f2bf(float f) {
    unsigned int x = __float_as_uint(f);
    x += 0x7fffu + ((x >> 16) & 1u);
    return (unsigned short)(x >> 16);
}

__device__ __forceinline__ bf16x8 ld_bf16x8(const unsigned short* p) {
    // two aligned 8 B LDS reads (b64); p is 8 B aligned by construction
    const short4 lo = *(const short4*)p;
    const short4 hi = *(const short4*)(p + 4);
    bf16x8 r = {lo.x, lo.y, lo.z, lo.w, hi.x, hi.y, hi.z, hi.w};
    return r;
}

// padded LDS strides (in bf16 elements): keep 16 B k-offsets 8 B-aligned,
// 2-way bank aliasing only (free on CDNA4, m136)
#define W1_STRIDE 264   // k-dim 256 + 8
#define W2_STRIDE 132   // k-dim 128 + 4
#define H1_STRIDE 132

// ---------------------------------------------------------------------------
// MLP: h[m,:] = relu(down[m,:] @ W1 + b1) @ W2 + b2, h stored as bf16.
// 256 persistent blocks x 512 threads (8 waves). Each block: stage W1^T/W2^T
// in LDS once, then 4 passes of 128 rows (16 rows per wave).
//
// R1 change vs previous version:
//  * sH tiles are per-wave-private -> the two per-pass __syncthreads() were
//    pure overhead (8-wave rendezvous at 2 waves/SIMD). Replaced with a
//    wave-local s_waitcnt lgkmcnt(0) ("memory" clobber = compiler fence).
//  * down-row loads double-buffered across passes (raw[2][16], pass loop
//    fully unrolled so all indices are compile-time): 16 float4 loads/wave
//    stay in flight under the MFMA/LDS phase instead of HBM idling.
// ---------------------------------------------------------------------------
__global__ __launch_bounds__(512, 2) void knn_mlp_mfma(
    const float* __restrict__ down, const float* __restrict__ W1,
    const float* __restrict__ b1,   const float* __restrict__ W2,
    const float* __restrict__ b2,   unsigned short* __restrict__ h)
{
    __shared__ unsigned short sW1t[DOUT * W1_STRIDE];        // [n][k] 66 KiB
    __shared__ unsigned short sW2t[DOUT * W2_STRIDE];        // [n][k] 33 KiB
    __shared__ unsigned short sH[8][16 * H1_STRIDE];         // per-wave 33 KiB

    const int tid = threadIdx.x;

    // ---- stage W1^T (bf16, transposed) ----
    #pragma unroll
    for (int it = 0; it < 16; ++it) {
        const int fid = it * 512 + tid;              // 8192 float4s of W1
        const int k = fid >> 5, n4 = (fid & 31) * 4;
        const float4 w = ((const float4*)W1)[fid];
        sW1t[(n4 + 0) * W1_STRIDE + k] = f2bf(w.x);
        sW1t[(n4 + 1) * W1_STRIDE + k] = f2bf(w.y);
        sW1t[(n4 + 2) * W1_STRIDE + k] = f2bf(w.z);
        sW1t[(n4 + 3) * W1_STRIDE + k] = f2bf(w.w);
    }
    // ---- stage W2^T ----
    #pragma unroll
    for (int it = 0; it < 8; ++it) {
        const int fid = it * 512 + tid;              // 4096 float4s of W2
        const int k = fid >> 5, n4 = (fid & 31) * 4;
        const float4 w = ((const float4*)W2)[fid];
        sW2t[(n4 + 0) * W2_STRIDE + k] = f2bf(w.x);
        sW2t[(n4 + 1) * W2_STRIDE + k] = f2bf(w.y);
        sW2t[(n4 + 2) * W2_STRIDE + k] = f2bf(w.z);
        sW2t[(n4 + 3) * W2_STRIDE + k] = f2bf(w.w);
    }
    __syncthreads();   // the ONLY workgroup barrier: weights staged

    const int wave = tid >> 6, lane = tid & 63;
    const int lm = lane & 15, lg = lane >> 4;
    unsigned short* hw = sH[wave];

    float b1r[8], b2r[8];
    #pragma unroll
    for (int nt = 0; nt < 8; ++nt) {
        b1r[nt] = b1[nt * 16 + lm];
        b2r[nt] = b2[nt * 16 + lm];
    }

    const int row0 = blockIdx.x * 512 + wave * 16;           // pass adds 128
    const float* dbase = down + (size_t)(row0 + lm) * DIN + lg * 8;

    // double-buffered raw rows: 16 float4 per pass (128 consecutive bytes
    // of each of this lane's 16 rows, split in two 16 B pieces)
    float4 raw[2][16];

    // prologue: pass 0 rows
    #pragma unroll
    for (int k = 0; k < 8; ++k) {
        raw[0][2 * k]     = *(const float4*)(dbase + k * 32);
        raw[0][2 * k + 1] = *(const float4*)(dbase + k * 32 + 4);
    }

    #pragma unroll
    for (int pass = 0; pass < 4; ++pass) {
        const int cur = pass & 1;
        const int chunk = row0 + pass * 128;

        // ---- issue next pass's 16 loads now; they fly under the MFMAs ----
        if (pass < 3) {
            const float* dp = dbase + (size_t)(pass + 1) * 128 * DIN;
            #pragma unroll
            for (int k = 0; k < 8; ++k) {
                raw[cur ^ 1][2 * k]     = *(const float4*)(dp + k * 32);
                raw[cur ^ 1][2 * k + 1] = *(const float4*)(dp + k * 32 + 4);
            }
        }

        // ---- layer 1: 256 -> 128 (A-frags converted inline from raw) ----
        f32x4 acc[8];
        #pragma unroll
        for (int nt = 0; nt < 8; ++nt) acc[nt] = (f32x4){0.f, 0.f, 0.f, 0.f};
        #pragma unroll
        for (int k = 0; k < 8; ++k) {
            const float4 r0 = raw[cur][2 * k], r1 = raw[cur][2 * k + 1];
            const bf16x8 a = {(short)f2bf(r0.x), (short)f2bf(r0.y), (short)f2bf(r0.z), (short)f2bf(r0.w),
                              (short)f2bf(r1.x), (short)f2bf(r1.y), (short)f2bf(r1.z), (short)f2bf(r1.w)};
            const int koff = k * 32 + lg * 8;
            #pragma unroll
            for (int nt = 0; nt < 8; ++nt) {
                const bf16x8 B = ld_bf16x8(&sW1t[(nt * 16 + lm) * W1_STRIDE + koff]);
                acc[nt] = __builtin_amdgcn_mfma_f32_16x16x32_bf16(a, B, acc[nt], 0, 0, 0);
            }
        }

        // relu + bias -> per-wave LDS tile (C-layout -> [m][k] for layer 2)
        #pragma unroll
        for (int nt = 0; nt < 8; ++nt) {
            #pragma unroll
            for (int i = 0; i < 4; ++i) {
                float v = acc[nt][i] + b1r[nt];
                v = fmaxf(v, 0.0f);
                hw[(lg * 4 + i) * H1_STRIDE + nt * 16 + lm] = f2bf(v);
            }
        }
        // wave-local write->read ordering on the private sH tile; the asm
        // "memory" clobber also stops the compiler sinking/hoisting LDS ops
        asm volatile("s_waitcnt lgkmcnt(0)" ::: "memory");

        // ---- layer 2: 128 -> 128 ----
        f32x4 acc2[8];
        #pragma unroll
        for (int nt = 0; nt < 8; ++nt) acc2[nt] = (f32x4){0.f, 0.f, 0.f, 0.f};
        #pragma unroll
        for (int k = 0; k < 4; ++k) {
            const int koff = k * 32 + lg * 8;
            const bf16x8 A2 = ld_bf16x8(&hw[lm * H1_STRIDE + koff]);
            #pragma unroll
            for (int nt = 0; nt < 8; ++nt) {
                const bf16x8 B = ld_bf16x8(&sW2t[(nt * 16 + lm) * W2_STRIDE + koff]);
                acc2[nt] = __builtin_amdgcn_mfma_f32_16x16x32_bf16(A2, B, acc2[nt], 0, 0, 0);
            }
        }

        // epilogue: + b2, cvt bf16, store to global h.
        // (WAR on sH for the next pass is safe: the MFMAs above already
        // forced lgkmcnt waits on the A2 reads, and per-wave DS ops to the
        // same buffer are kept in order by the compiler's alias analysis.)
        #pragma unroll
        for (int nt = 0; nt < 8; ++nt) {
            #pragma unroll
            for (int i = 0; i < 4; ++i) {
                const float v = acc2[nt][i] + b2r[nt];
                h[(size_t)(chunk + lg * 4 + i) * DOUT + nt * 16 + lm] = f2bf(v);
            }
        }
    }
}

// ---------------------------------------------------------------------------
// Gather: out[p,:] = up[p,:] + mean_k h_bf16[idx[p,k]*8 + n, :]
// One wave per 64 pairs (grid-stride free), 4-pair unroll -> 16 loads in
// flight. Lane covers 2 of 128 cols (one uint = 2 bf16 / one float2).
// ---------------------------------------------------------------------------
__global__ __launch_bounds__(256) void knn_gather(
    const float* __restrict__ up, const int* __restrict__ idx,
    const unsigned int* __restrict__ h32, float* __restrict__ out)
{
    const int wave = threadIdx.x >> 6, lane = threadIdx.x & 63;
    const long long wid  = (long long)blockIdx.x * 4 + wave;   // 8192 waves
    const long long base = wid * 64;                           // pairs/wave

    for (int p0 = 0; p0 < 64; p0 += 4) {
        const long long pair0 = base + p0;
        // 12 consecutive ints of idx (16 B aligned)
        const int4* ip = (const int4*)(idx + pair0 * 3);
        const int4 q0 = ip[0], q1 = ip[1], q2 = ip[2];
        const int id[4][3] = {{q0.x, q0.y, q0.z}, {q0.w, q1.x, q1.y},
                              {q1.z, q1.w, q2.x}, {q2.y, q2.z, q2.w}};

        unsigned int ga[4][3];
        float2 uu[4];
        #pragma unroll
        for (int u = 0; u < 4; ++u) {
            const long long pair = pair0 + u;
            const int n = (int)(pair & 7);
            ga[u][0] = h32[((size_t)id[u][0] * 8 + n) * 64 + lane];
            ga[u][1] = h32[((size_t)id[u][1] * 8 + n) * 64 + lane];
            ga[u][2] = h32[((size_t)id[u][2] * 8 + n) * 64 + lane];
            uu[u] = ((const float2*)up)[pair * 64 + lane];
        }
        #pragma unroll
        for (int u = 0; u < 4; ++u) {
            float sx = 0.f, sy = 0.f;
            #pragma unroll
            for (int j = 0; j < 3; ++j) {
                const unsigned int v = ga[u][j];
                sx += __uint_as_float(v << 16);
                sy += __uint_as_float(v & 0xffff0000u);
            }
            float2 o;
            o.x = uu[u].x + sx * (1.0f / 3.0f);
            o.y = uu[u].y + sy * (1.0f / 3.0f);
            ((float2*)out)[(pair0 + u) * 64 + lane] = o;
        }
    }
}

// ---------------------------------------------------------------------------
extern "C" void kernel_launch(void* const* d_in, const int* in_sizes, int n_in,
                              void* d_out, int out_size, void* d_ws, size_t ws_size,
                              hipStream_t stream)
{
    const float* down = (const float*)d_in[0];
    const float* up   = (const float*)d_in[1];
    const int*   idx  = (const int*)d_in[2];
    const float* W1   = (const float*)d_in[3];
    const float* b1   = (const float*)d_in[4];
    const float* W2   = (const float*)d_in[5];
    const float* b2   = (const float*)d_in[6];
    float* out = (float*)d_out;
    unsigned short* h = (unsigned short*)d_ws;   // M_ x 128 bf16 = 32 MiB

    knn_mlp_mfma<<<256, 512, 0, stream>>>(down, W1, b1, W2, b2, h);
    knn_gather<<<2048, 256, 0, stream>>>(up, idx, (const unsigned int*)h, out);
}

// Round 3
// 562.982 us; speedup vs baseline: 1.0420x; 1.0260x over previous
//
#include <hip/hip_runtime.h>

#define LD_   16384
#define LU_   65536
#define N_    8
#define DIN   256
#define DOUT  128
#define K_    3
#define M_    (LD_ * N_)   // 131072 rows through the MLP

typedef short bf16x8 __attribute__((ext_vector_type(8)));
typedef float f32x4  __attribute__((ext_vector_type(4)));
typedef unsigned int u32x2 __attribute__((ext_vector_type(2)));

// fp32 -> bf16 round-to-nearest-even (inputs finite, no NaN handling)
__device__ __forceinline__ unsigned short f2bf(float f) {
    unsigned int x = __float_as_uint(f);
    x += 0x7fffu + ((x >> 16) & 1u);
    return (unsigned short)(x >> 16);
}

__device__ __forceinline__ bf16x8 ld_bf16x8(const unsigned short* p) {
    // two aligned 8 B LDS reads (b64); p is 8 B aligned by construction
    const short4 lo = *(const short4*)p;
    const short4 hi = *(const short4*)(p + 4);
    bf16x8 r = {lo.x, lo.y, lo.z, lo.w, hi.x, hi.y, hi.z, hi.w};
    return r;
}

// padded LDS strides (in bf16 elements): keep 16 B k-offsets 8 B-aligned,
// 2-way bank aliasing only (free on CDNA4, m136)
#define W1_STRIDE 264   // k-dim 256 + 8
#define W2_STRIDE 132   // k-dim 128 + 4
#define H1_STRIDE 132

// ---------------------------------------------------------------------------
// MLP: h[m,:] = relu(down[m,:] @ W1 + b1) @ W2 + b2, h stored as bf16.
// 256 persistent blocks x 512 threads (8 waves). Each block: stage W1^T/W2^T
// in LDS once, then 4 passes of 128 rows (16 rows per wave).
// (unchanged from R1 — per-wave-private sH, no per-pass barriers, down rows
//  double-buffered across passes)
// ---------------------------------------------------------------------------
__global__ __launch_bounds__(512, 2) void knn_mlp_mfma(
    const float* __restrict__ down, const float* __restrict__ W1,
    const float* __restrict__ b1,   const float* __restrict__ W2,
    const float* __restrict__ b2,   unsigned short* __restrict__ h)
{
    __shared__ unsigned short sW1t[DOUT * W1_STRIDE];        // [n][k] 66 KiB
    __shared__ unsigned short sW2t[DOUT * W2_STRIDE];        // [n][k] 33 KiB
    __shared__ unsigned short sH[8][16 * H1_STRIDE];         // per-wave 33 KiB

    const int tid = threadIdx.x;

    // ---- stage W1^T (bf16, transposed) ----
    #pragma unroll
    for (int it = 0; it < 16; ++it) {
        const int fid = it * 512 + tid;              // 8192 float4s of W1
        const int k = fid >> 5, n4 = (fid & 31) * 4;
        const float4 w = ((const float4*)W1)[fid];
        sW1t[(n4 + 0) * W1_STRIDE + k] = f2bf(w.x);
        sW1t[(n4 + 1) * W1_STRIDE + k] = f2bf(w.y);
        sW1t[(n4 + 2) * W1_STRIDE + k] = f2bf(w.z);
        sW1t[(n4 + 3) * W1_STRIDE + k] = f2bf(w.w);
    }
    // ---- stage W2^T ----
    #pragma unroll
    for (int it = 0; it < 8; ++it) {
        const int fid = it * 512 + tid;              // 4096 float4s of W2
        const int k = fid >> 5, n4 = (fid & 31) * 4;
        const float4 w = ((const float4*)W2)[fid];
        sW2t[(n4 + 0) * W2_STRIDE + k] = f2bf(w.x);
        sW2t[(n4 + 1) * W2_STRIDE + k] = f2bf(w.y);
        sW2t[(n4 + 2) * W2_STRIDE + k] = f2bf(w.z);
        sW2t[(n4 + 3) * W2_STRIDE + k] = f2bf(w.w);
    }
    __syncthreads();   // the ONLY workgroup barrier: weights staged

    const int wave = tid >> 6, lane = tid & 63;
    const int lm = lane & 15, lg = lane >> 4;
    unsigned short* hw = sH[wave];

    float b1r[8], b2r[8];
    #pragma unroll
    for (int nt = 0; nt < 8; ++nt) {
        b1r[nt] = b1[nt * 16 + lm];
        b2r[nt] = b2[nt * 16 + lm];
    }

    const int row0 = blockIdx.x * 512 + wave * 16;           // pass adds 128
    const float* dbase = down + (size_t)(row0 + lm) * DIN + lg * 8;

    // double-buffered raw rows: 16 float4 per pass
    float4 raw[2][16];

    // prologue: pass 0 rows
    #pragma unroll
    for (int k = 0; k < 8; ++k) {
        raw[0][2 * k]     = *(const float4*)(dbase + k * 32);
        raw[0][2 * k + 1] = *(const float4*)(dbase + k * 32 + 4);
    }

    #pragma unroll
    for (int pass = 0; pass < 4; ++pass) {
        const int cur = pass & 1;
        const int chunk = row0 + pass * 128;

        // ---- issue next pass's 16 loads now; they fly under the MFMAs ----
        if (pass < 3) {
            const float* dp = dbase + (size_t)(pass + 1) * 128 * DIN;
            #pragma unroll
            for (int k = 0; k < 8; ++k) {
                raw[cur ^ 1][2 * k]     = *(const float4*)(dp + k * 32);
                raw[cur ^ 1][2 * k + 1] = *(const float4*)(dp + k * 32 + 4);
            }
        }

        // ---- layer 1: 256 -> 128 ----
        f32x4 acc[8];
        #pragma unroll
        for (int nt = 0; nt < 8; ++nt) acc[nt] = (f32x4){0.f, 0.f, 0.f, 0.f};
        #pragma unroll
        for (int k = 0; k < 8; ++k) {
            const float4 r0 = raw[cur][2 * k], r1 = raw[cur][2 * k + 1];
            const bf16x8 a = {(short)f2bf(r0.x), (short)f2bf(r0.y), (short)f2bf(r0.z), (short)f2bf(r0.w),
                              (short)f2bf(r1.x), (short)f2bf(r1.y), (short)f2bf(r1.z), (short)f2bf(r1.w)};
            const int koff = k * 32 + lg * 8;
            #pragma unroll
            for (int nt = 0; nt < 8; ++nt) {
                const bf16x8 B = ld_bf16x8(&sW1t[(nt * 16 + lm) * W1_STRIDE + koff]);
                acc[nt] = __builtin_amdgcn_mfma_f32_16x16x32_bf16(a, B, acc[nt], 0, 0, 0);
            }
        }

        // relu + bias -> per-wave LDS tile (C-layout -> [m][k] for layer 2)
        #pragma unroll
        for (int nt = 0; nt < 8; ++nt) {
            #pragma unroll
            for (int i = 0; i < 4; ++i) {
                float v = acc[nt][i] + b1r[nt];
                v = fmaxf(v, 0.0f);
                hw[(lg * 4 + i) * H1_STRIDE + nt * 16 + lm] = f2bf(v);
            }
        }
        // wave-local write->read ordering on the private sH tile
        asm volatile("s_waitcnt lgkmcnt(0)" ::: "memory");

        // ---- layer 2: 128 -> 128 ----
        f32x4 acc2[8];
        #pragma unroll
        for (int nt = 0; nt < 8; ++nt) acc2[nt] = (f32x4){0.f, 0.f, 0.f, 0.f};
        #pragma unroll
        for (int k = 0; k < 4; ++k) {
            const int koff = k * 32 + lg * 8;
            const bf16x8 A2 = ld_bf16x8(&hw[lm * H1_STRIDE + koff]);
            #pragma unroll
            for (int nt = 0; nt < 8; ++nt) {
                const bf16x8 B = ld_bf16x8(&sW2t[(nt * 16 + lm) * W2_STRIDE + koff]);
                acc2[nt] = __builtin_amdgcn_mfma_f32_16x16x32_bf16(A2, B, acc2[nt], 0, 0, 0);
            }
        }

        // epilogue: + b2, cvt bf16, store to global h
        #pragma unroll
        for (int nt = 0; nt < 8; ++nt) {
            #pragma unroll
            for (int i = 0; i < 4; ++i) {
                const float v = acc2[nt][i] + b2r[nt];
                h[(size_t)(chunk + lg * 4 + i) * DOUT + nt * 16 + lm] = f2bf(v);
            }
        }
    }
}

// ---------------------------------------------------------------------------
// Gather: out[p,:] = up[p,:] + mean_k h_bf16[idx[p,k]*8 + n, :]
//
// R2/R3 restructure:
//  * lane l pre-loads ALL 3 idx of pair (base+l) once; per-group retrieval
//    via __shfl -> no idx->gather latency chain in the loop.
//  * half-wave-per-pair: lanes 0-31 = pair p, lanes 32-63 = pair p+1.
//    up/out as 16 B/lane (native f32x4 for nontemporal builtins), h rows as
//    uint2 (8 B/lane, one 256 B row per half-wave). ~40% fewer memory
//    instructions per pair.
//  * nontemporal load/store for streamed-once up/out (keep LLC for h).
// ---------------------------------------------------------------------------
__global__ __launch_bounds__(256) void knn_gather(
    const float* __restrict__ up, const int* __restrict__ idx,
    const unsigned int* __restrict__ h32, float* __restrict__ out)
{
    const int wave = threadIdx.x >> 6, lane = threadIdx.x & 63;
    const int half = lane >> 5, lih = lane & 31;
    const long long wid  = (long long)blockIdx.x * 4 + wave;   // 8192 waves
    const long long base = wid * 64;                           // pairs/wave

    // lane l owns the 3 neighbor indices of pair (base + l)
    const int* ip = idx + (base + lane) * 3;
    const int mi0 = ip[0], mi1 = ip[1], mi2 = ip[2];

    const u32x2* hg   = (const u32x2*)h32;      // h row = 32 uint2 (256 B)
    const f32x4* upv  = (const f32x4*)up;       // up row = 32 float4 (512 B)
    f32x4*       outv = (f32x4*)out;

    #pragma unroll
    for (int gb = 0; gb < 8; ++gb) {            // 8 batches x 4 groups x 2 pairs
        u32x2 ga[4][3];
        f32x4 uu[4];
        int   pp[4];
        #pragma unroll
        for (int u = 0; u < 4; ++u) {
            const int p = (gb * 4 + u) * 2 + half;     // pair-in-wave 0..63
            pp[u] = p;
            const int i0 = __shfl(mi0, p);
            const int i1 = __shfl(mi1, p);
            const int i2 = __shfl(mi2, p);
            const int n  = p & 7;                      // base % 8 == 0
            ga[u][0] = hg[(unsigned)(i0 * 8 + n) * 32u + lih];
            ga[u][1] = hg[(unsigned)(i1 * 8 + n) * 32u + lih];
            ga[u][2] = hg[(unsigned)(i2 * 8 + n) * 32u + lih];
            uu[u] = __builtin_nontemporal_load(&upv[(base + p) * 32 + lih]);
        }
        #pragma unroll
        for (int u = 0; u < 4; ++u) {
            float s0 = 0.f, s1 = 0.f, s2 = 0.f, s3 = 0.f;
            #pragma unroll
            for (int j = 0; j < 3; ++j) {
                const u32x2 v = ga[u][j];
                s0 += __uint_as_float(v.x << 16);
                s1 += __uint_as_float(v.x & 0xffff0000u);
                s2 += __uint_as_float(v.y << 16);
                s3 += __uint_as_float(v.y & 0xffff0000u);
            }
            f32x4 o;
            o.x = uu[u].x + s0 * (1.0f / 3.0f);
            o.y = uu[u].y + s1 * (1.0f / 3.0f);
            o.z = uu[u].z + s2 * (1.0f / 3.0f);
            o.w = uu[u].w + s3 * (1.0f / 3.0f);
            __builtin_nontemporal_store(o, &outv[(base + pp[u]) * 32 + lih]);
        }
    }
}

// ---------------------------------------------------------------------------
extern "C" void kernel_launch(void* const* d_in, const int* in_sizes, int n_in,
                              void* d_out, int out_size, void* d_ws, size_t ws_size,
                              hipStream_t stream)
{
    const float* down = (const float*)d_in[0];
    const float* up   = (const float*)d_in[1];
    const int*   idx  = (const int*)d_in[2];
    const float* W1   = (const float*)d_in[3];
    const float* b1   = (const float*)d_in[4];
    const float* W2   = (const float*)d_in[5];
    const float* b2   = (const float*)d_in[6];
    float* out = (float*)d_out;
    unsigned short* h = (unsigned short*)d_ws;   // M_ x 128 bf16 = 32 MiB

    knn_mlp_mfma<<<256, 512, 0, stream>>>(down, W1, b1, W2, b2, h);
    knn_gather<<<2048, 256, 0, stream>>>(up, idx, (const unsigned int*)h, out);
}

// Round 4
// 554.708 us; speedup vs baseline: 1.0576x; 1.0149x over previous
//
#include <hip/hip_runtime.h>

#define LD_   16384
#define LU_   65536
#define N_    8
#define DIN   256
#define DOUT  128
#define K_    3
#define M_    (LD_ * N_)   // 131072 rows through the MLP

typedef short bf16x8 __attribute__((ext_vector_type(8)));
typedef float f32x4  __attribute__((ext_vector_type(4)));
typedef unsigned int u32x2 __attribute__((ext_vector_type(2)));

// fp32 -> bf16 round-to-nearest-even (inputs finite, no NaN handling)
__device__ __forceinline__ unsigned short f2bf(float f) {
    unsigned int x = __float_as_uint(f);
    x += 0x7fffu + ((x >> 16) & 1u);
    return (unsigned short)(x >> 16);
}

__device__ __forceinline__ bf16x8 ld_bf16x8(const unsigned short* p) {
    // two aligned 8 B LDS reads (b64); p is 8 B aligned by construction
    const short4 lo = *(const short4*)p;
    const short4 hi = *(const short4*)(p + 4);
    bf16x8 r = {lo.x, lo.y, lo.z, lo.w, hi.x, hi.y, hi.z, hi.w};
    return r;
}

// padded LDS strides (in bf16 elements): keep 16 B k-offsets 8 B-aligned,
// 2-way bank aliasing only (free on CDNA4, m136)
#define W1_STRIDE 264   // k-dim 256 + 8
#define W2_STRIDE 132   // k-dim 128 + 4
#define H1_STRIDE 132

// ---------------------------------------------------------------------------
// MLP: h[m,:] = relu(down[m,:] @ W1 + b1) @ W2 + b2, h stored as bf16.
// 256 persistent blocks x 512 threads (8 waves), 4 passes of 128 rows
// (16 rows/wave/pass).
//
// R4: SWAPPED-OPERAND MFMA (D = W^T . x^T). Fragment data is identical to
// the old orientation (W^T LDS read was the old B-frag, down-row regs were
// the old A-frag) but the C/D layout transposes: lane lm = row m, regs i =
// 4 CONSECUTIVE output features nt*16+lg*4+i. This packs:
//   - sH spill:   32 ds_write_u16  -> 8 ds_write_b64 per pass
//   - h store:    32 x 2 B scalars -> 8 x 8 B stores per pass
// Biases become per-reg-indexed -> 1 KiB LDS table (lm-broadcast reads).
// Pass-0 down loads issued BEFORE W staging (overlap serial prologue);
// single raw[] buffer, convert-at-top + reissue (same overlap, -64 VGPR).
// Per-wave-private sH -> no per-pass barriers (R1).
// ---------------------------------------------------------------------------
__global__ __launch_bounds__(512, 2) void knn_mlp_mfma(
    const float* __restrict__ down, const float* __restrict__ W1,
    const float* __restrict__ b1,   const float* __restrict__ W2,
    const float* __restrict__ b2,   unsigned short* __restrict__ h)
{
    __shared__ unsigned short sW1t[DOUT * W1_STRIDE];        // [n][k] 66 KiB
    __shared__ unsigned short sW2t[DOUT * W2_STRIDE];        // [n][k] 33 KiB
    __shared__ unsigned short sH[8][16 * H1_STRIDE];         // per-wave 33 KiB
    __shared__ float sB1[DOUT], sB2[DOUT];                   // 1 KiB

    const int tid  = threadIdx.x;
    const int wave = tid >> 6, lane = tid & 63;
    const int lm = lane & 15, lg = lane >> 4;

    const int row0 = blockIdx.x * 512 + wave * 16;           // pass adds 128
    const float* dbase = down + (size_t)(row0 + lm) * DIN + lg * 8;

    // ---- issue pass-0 row loads FIRST: they fly under the W staging ----
    float4 raw[16];
    #pragma unroll
    for (int k = 0; k < 8; ++k) {
        raw[2 * k]     = *(const float4*)(dbase + k * 32);
        raw[2 * k + 1] = *(const float4*)(dbase + k * 32 + 4);
    }

    // ---- stage W1^T (bf16, transposed) ----
    #pragma unroll
    for (int it = 0; it < 16; ++it) {
        const int fid = it * 512 + tid;              // 8192 float4s of W1
        const int k = fid >> 5, n4 = (fid & 31) * 4;
        const float4 w = ((const float4*)W1)[fid];
        sW1t[(n4 + 0) * W1_STRIDE + k] = f2bf(w.x);
        sW1t[(n4 + 1) * W1_STRIDE + k] = f2bf(w.y);
        sW1t[(n4 + 2) * W1_STRIDE + k] = f2bf(w.z);
        sW1t[(n4 + 3) * W1_STRIDE + k] = f2bf(w.w);
    }
    // ---- stage W2^T ----
    #pragma unroll
    for (int it = 0; it < 8; ++it) {
        const int fid = it * 512 + tid;              // 4096 float4s of W2
        const int k = fid >> 5, n4 = (fid & 31) * 4;
        const float4 w = ((const float4*)W2)[fid];
        sW2t[(n4 + 0) * W2_STRIDE + k] = f2bf(w.x);
        sW2t[(n4 + 1) * W2_STRIDE + k] = f2bf(w.y);
        sW2t[(n4 + 2) * W2_STRIDE + k] = f2bf(w.z);
        sW2t[(n4 + 3) * W2_STRIDE + k] = f2bf(w.w);
    }
    // ---- stage biases (f32, 128 each) ----
    if (tid < 32)                 ((float4*)sB1)[tid]      = ((const float4*)b1)[tid];
    else if (tid < 64)            ((float4*)sB2)[tid - 32] = ((const float4*)b2)[tid - 32];
    __syncthreads();   // the ONLY workgroup barrier: weights staged

    unsigned short* hw = sH[wave];

    #pragma unroll
    for (int pass = 0; pass < 4; ++pass) {
        const int chunk = row0 + pass * 128;

        // ---- convert in-flight rows to B-frags (down^T): forces the vmcnt
        //      wait; raw regs then free for the next pass's loads ----
        bf16x8 A[8];
        #pragma unroll
        for (int k = 0; k < 8; ++k) {
            const float4 r0 = raw[2 * k], r1 = raw[2 * k + 1];
            const bf16x8 a = {(short)f2bf(r0.x), (short)f2bf(r0.y), (short)f2bf(r0.z), (short)f2bf(r0.w),
                              (short)f2bf(r1.x), (short)f2bf(r1.y), (short)f2bf(r1.z), (short)f2bf(r1.w)};
            A[k] = a;
        }

        // ---- issue next pass's 16 loads: they fly under the MFMAs ----
        if (pass < 3) {
            const float* dp = dbase + (size_t)(pass + 1) * 128 * DIN;
            #pragma unroll
            for (int k = 0; k < 8; ++k) {
                raw[2 * k]     = *(const float4*)(dp + k * 32);
                raw[2 * k + 1] = *(const float4*)(dp + k * 32 + 4);
            }
        }

        // ---- layer 1: D1 = W1^T . down^T  (D1[n1][m], lane: m=lm,
        //      n1 = nt*16 + lg*4 + i) ----
        f32x4 acc[8];
        #pragma unroll
        for (int nt = 0; nt < 8; ++nt) acc[nt] = (f32x4){0.f, 0.f, 0.f, 0.f};
        #pragma unroll
        for (int k = 0; k < 8; ++k) {
            const int koff = k * 32 + lg * 8;
            #pragma unroll
            for (int nt = 0; nt < 8; ++nt) {
                const bf16x8 Wf = ld_bf16x8(&sW1t[(nt * 16 + lm) * W1_STRIDE + koff]);
                acc[nt] = __builtin_amdgcn_mfma_f32_16x16x32_bf16(Wf, A[k], acc[nt], 0, 0, 0);
            }
        }

        // relu + bias -> per-wave LDS tile, PACKED: 4 consecutive n1 per reg
        // quad -> one ds_write_b64 per nt. sH layout [m][k] (k = n1).
        #pragma unroll
        for (int nt = 0; nt < 8; ++nt) {
            const float4 bq = *(const float4*)&sB1[nt * 16 + lg * 4];
            ushort4 st;
            st.x = f2bf(fmaxf(acc[nt][0] + bq.x, 0.0f));
            st.y = f2bf(fmaxf(acc[nt][1] + bq.y, 0.0f));
            st.z = f2bf(fmaxf(acc[nt][2] + bq.z, 0.0f));
            st.w = f2bf(fmaxf(acc[nt][3] + bq.w, 0.0f));
            *(ushort4*)&hw[lm * H1_STRIDE + nt * 16 + lg * 4] = st;
        }
        // wave-local write->read ordering on the private sH tile
        asm volatile("s_waitcnt lgkmcnt(0)" ::: "memory");

        // ---- layer 2: D2 = W2^T . h1^T  (lane: m=lm, n2=nt*16+lg*4+i) ----
        f32x4 acc2[8];
        #pragma unroll
        for (int nt = 0; nt < 8; ++nt) acc2[nt] = (f32x4){0.f, 0.f, 0.f, 0.f};
        #pragma unroll
        for (int ks = 0; ks < 4; ++ks) {
            const int koff = ks * 32 + lg * 8;
            const bf16x8 Bh = ld_bf16x8(&hw[lm * H1_STRIDE + koff]);   // h1[lm][k..k+7]
            #pragma unroll
            for (int nt = 0; nt < 8; ++nt) {
                const bf16x8 Wf = ld_bf16x8(&sW2t[(nt * 16 + lm) * W2_STRIDE + koff]);
                acc2[nt] = __builtin_amdgcn_mfma_f32_16x16x32_bf16(Wf, Bh, acc2[nt], 0, 0, 0);
            }
        }

        // epilogue: + b2, cvt bf16, PACKED 8 B stores (4 consecutive cols)
        #pragma unroll
        for (int nt = 0; nt < 8; ++nt) {
            const float4 bq = *(const float4*)&sB2[nt * 16 + lg * 4];
            ushort4 st;
            st.x = f2bf(acc2[nt][0] + bq.x);
            st.y = f2bf(acc2[nt][1] + bq.y);
            st.z = f2bf(acc2[nt][2] + bq.z);
            st.w = f2bf(acc2[nt][3] + bq.w);
            *(ushort4*)&h[(size_t)(chunk + lm) * DOUT + nt * 16 + lg * 4] = st;
        }
    }
}

// ---------------------------------------------------------------------------
// Gather: out[p,:] = up[p,:] + mean_k h_bf16[idx[p,k]*8 + n, :]
// (unchanged from R3 — idx pre-load + __shfl, half-wave-per-pair, f32x4
//  nontemporal up/out, uint2 h-row gathers)
// ---------------------------------------------------------------------------
__global__ __launch_bounds__(256) void knn_gather(
    const float* __restrict__ up, const int* __restrict__ idx,
    const unsigned int* __restrict__ h32, float* __restrict__ out)
{
    const int wave = threadIdx.x >> 6, lane = threadIdx.x & 63;
    const int half = lane >> 5, lih = lane & 31;
    const long long wid  = (long long)blockIdx.x * 4 + wave;   // 8192 waves
    const long long base = wid * 64;                           // pairs/wave

    // lane l owns the 3 neighbor indices of pair (base + l)
    const int* ip = idx + (base + lane) * 3;
    const int mi0 = ip[0], mi1 = ip[1], mi2 = ip[2];

    const u32x2* hg   = (const u32x2*)h32;      // h row = 32 uint2 (256 B)
    const f32x4* upv  = (const f32x4*)up;       // up row = 32 float4 (512 B)
    f32x4*       outv = (f32x4*)out;

    #pragma unroll
    for (int gb = 0; gb < 8; ++gb) {            // 8 batches x 4 groups x 2 pairs
        u32x2 ga[4][3];
        f32x4 uu[4];
        int   pp[4];
        #pragma unroll
        for (int u = 0; u < 4; ++u) {
            const int p = (gb * 4 + u) * 2 + half;     // pair-in-wave 0..63
            pp[u] = p;
            const int i0 = __shfl(mi0, p);
            const int i1 = __shfl(mi1, p);
            const int i2 = __shfl(mi2, p);
            const int n  = p & 7;                      // base % 8 == 0
            ga[u][0] = hg[(unsigned)(i0 * 8 + n) * 32u + lih];
            ga[u][1] = hg[(unsigned)(i1 * 8 + n) * 32u + lih];
            ga[u][2] = hg[(unsigned)(i2 * 8 + n) * 32u + lih];
            uu[u] = __builtin_nontemporal_load(&upv[(base + p) * 32 + lih]);
        }
        #pragma unroll
        for (int u = 0; u < 4; ++u) {
            float s0 = 0.f, s1 = 0.f, s2 = 0.f, s3 = 0.f;
            #pragma unroll
            for (int j = 0; j < 3; ++j) {
                const u32x2 v = ga[u][j];
                s0 += __uint_as_float(v.x << 16);
                s1 += __uint_as_float(v.x & 0xffff0000u);
                s2 += __uint_as_float(v.y << 16);
                s3 += __uint_as_float(v.y & 0xffff0000u);
            }
            f32x4 o;
            o.x = uu[u].x + s0 * (1.0f / 3.0f);
            o.y = uu[u].y + s1 * (1.0f / 3.0f);
            o.z = uu[u].z + s2 * (1.0f / 3.0f);
            o.w = uu[u].w + s3 * (1.0f / 3.0f);
            __builtin_nontemporal_store(o, &outv[(base + pp[u]) * 32 + lih]);
        }
    }
}

// ---------------------------------------------------------------------------
extern "C" void kernel_launch(void* const* d_in, const int* in_sizes, int n_in,
                              void* d_out, int out_size, void* d_ws, size_t ws_size,
                              hipStream_t stream)
{
    const float* down = (const float*)d_in[0];
    const float* up   = (const float*)d_in[1];
    const int*   idx  = (const int*)d_in[2];
    const float* W1   = (const float*)d_in[3];
    const float* b1   = (const float*)d_in[4];
    const float* W2   = (const float*)d_in[5];
    const float* b2   = (const float*)d_in[6];
    float* out = (float*)d_out;
    unsigned short* h = (unsigned short*)d_ws;   // M_ x 128 bf16 = 32 MiB

    knn_mlp_mfma<<<256, 512, 0, stream>>>(down, W1, b1, W2, b2, h);
    knn_gather<<<2048, 256, 0, stream>>>(up, idx, (const unsigned int*)h, out);
}